// Round 7
// baseline (465.366 us; speedup 1.0000x reference)
//
#include <hip/hip_runtime.h>
#include <hip/hip_cooperative_groups.h>

namespace cg = cooperative_groups;

#define IN_F 128
#define HID_F 64
#define BKT_SHIFT 9            // 512 nodes per bucket (R4-verified geometry)
#define BKT_SIZE 512
#define CHUNK 4096             // edges per block in binning phases

typedef unsigned short ushort_t;
typedef __attribute__((ext_vector_type(8))) short bf16x8;
typedef __attribute__((ext_vector_type(8))) unsigned short u16x8;
typedef __attribute__((ext_vector_type(4))) float f32x4;

__device__ inline ushort_t f2bf(float f) {     // RNE fp32 -> bf16 bits
    unsigned u = __float_as_uint(f);
    u += 0x7FFFu + ((u >> 16) & 1u);
    return (ushort_t)(u >> 16);
}
__device__ inline float bf2f(ushort_t u) {
    return __uint_as_float((unsigned)u << 16);
}

// ---------------- cooperative CSR build: all 5 phases in ONE kernel ----------------
// pack: (dst & 511) << 23 | src   (needs src < 2^23, nodes/bucket <= 512)
// Phases separated by grid.sync() (harness supports hipLaunchCooperativeKernel).
// Grid = nbE + 48 = 439 blocks of 256 — well under co-residency capacity (2048).
// LDS: one 1280-int buffer reused by every phase (5 KB).
__global__ __launch_bounds__(256) void k_csr(const int* __restrict__ src,
        const int* __restrict__ dst, int* __restrict__ ghist,
        int* __restrict__ gcount, int* __restrict__ gbase, int* __restrict__ bbase,
        int* __restrict__ rowptr, float* __restrict__ dinv,
        unsigned* __restrict__ gbin, int* __restrict__ col,
        const float* __restrict__ W1, const float* __restrict__ W2,
        ushort_t* __restrict__ Bp1, ushort_t* __restrict__ Bp2,
        int E, int N, int nbE, int nbB) {
    cg::grid_group grid = cg::this_grid();
    __shared__ int sh[1280];
    int tid = threadIdx.x;
    int bid = blockIdx.x;

    // ---- P0: per-block LDS histogram -> ghist; extra blocks do the W pre-pack ----
    if (bid < nbE) {
        sh[tid] = 0;
        __syncthreads();
        int e0 = bid * CHUNK, e1 = min(e0 + CHUNK, E);
        for (int e = e0 + tid; e < e1; e += 256)
            atomicAdd(&sh[dst[e] >> BKT_SHIFT], 1);
        __syncthreads();
        ghist[bid * 256 + tid] = sh[tid];
    } else {
        // W pre-pack into MFMA B-fragment order (bf16).
        // B-frag (16x16x32): lane holds B[k=(lane>>4)*8+j][n=lane&15], j=0..7.
        int id = (bid - nbE) * 256 + tid;
        int iw = (id < 8192) ? id : id - 8192;
        int j = iw & 7, lane = (iw >> 3) & 63, t = (iw >> 9) & 3, s = iw >> 11;
        int k = s * 32 + ((lane >> 4) << 3) + j;
        int n = t * 16 + (lane & 15);
        if (id < 8192)        Bp1[iw] = f2bf(W1[k * 64 + n]);   // K=128: s in 0..3
        else if (id < 12288)  Bp2[iw] = f2bf(W2[k * 64 + n]);   // K=64 : s in 0..1
    }
    grid.sync();

    // ---- P1: 256 blocks: exclusive scan of per-block counts per bucket ----
    if (bid < 256) {
        int b = bid;
        int j0 = 2 * tid, j1 = 2 * tid + 1;
        int v0 = (j0 < nbE) ? ghist[j0 * 256 + b] : 0;
        int v1 = (j1 < nbE) ? ghist[j1 * 256 + b] : 0;
        int p = v0 + v1;
        sh[tid] = p;
        __syncthreads();
        for (int off = 1; off < 256; off <<= 1) {
            int v = (tid >= off) ? sh[tid - off] : 0;
            __syncthreads();
            sh[tid] += v;
            __syncthreads();
        }
        int excl = sh[tid] - p;
        if (j0 < nbE) ghist[j0 * 256 + b] = excl;
        if (j1 < nbE) ghist[j1 * 256 + b] = excl + v0;
        if (tid == 255) gcount[b] = sh[255];
    }
    grid.sync();

    // ---- P2: block 0: exclusive scan of 256 bucket totals ----
    if (bid == 0) {
        int c = gcount[tid];
        sh[tid] = c;
        __syncthreads();
        for (int off = 1; off < 256; off <<= 1) {
            int v = (tid >= off) ? sh[tid - off] : 0;
            __syncthreads();
            sh[tid] += v;
            __syncthreads();
        }
        int base = sh[tid] - c;
        gbase[tid] = base;
        bbase[tid] = base;
        if (tid == 255) bbase[256] = sh[255];   // == E
        if (tid == 0) rowptr[N] = E;
    }
    grid.sync();

    // ---- P3: scatter into bucket-contiguous gbin (LDS cursors) ----
    if (bid < nbE) {
        sh[tid] = ghist[bid * 256 + tid] + gbase[tid];
        __syncthreads();
        int e0 = bid * CHUNK, e1 = min(e0 + CHUNK, E);
        for (int e = e0 + tid; e < e1; e += 256) {
            int d = dst[e];
            int b = d >> BKT_SHIFT;
            int p = atomicAdd(&sh[b], 1);
            gbin[p] = ((unsigned)(d & (BKT_SIZE - 1)) << 23) | (unsigned)src[e];
        }
        __syncthreads();
    }
    grid.sync();

    // ---- P4: one block per bucket: count, scan 512, rowptr/dinv, scatter col ----
    if (bid < nbB) {
        int* cnt = sh;            // [512]
        int* pos = sh + 512;      // [512]
        int* s   = sh + 1024;     // [256]
        int b = bid;
        int e0 = bbase[b], e1 = bbase[b + 1];
        cnt[tid] = 0; cnt[tid + 256] = 0;
        __syncthreads();
        for (int e = e0 + tid; e < e1; e += 256)
            atomicAdd(&cnt[gbin[e] >> 23], 1);
        __syncthreads();
        int c0 = cnt[2 * tid], c1 = cnt[2 * tid + 1];
        int p2 = c0 + c1;
        s[tid] = p2;
        __syncthreads();
        for (int off = 1; off < 256; off <<= 1) {
            int v = (tid >= off) ? s[tid - off] : 0;
            __syncthreads();
            s[tid] += v;
            __syncthreads();
        }
        int excl = s[tid] - p2;
        pos[2 * tid] = excl;
        pos[2 * tid + 1] = excl + c0;
        __syncthreads();
        int n0 = b << BKT_SHIFT;
        #pragma unroll
        for (int i = tid; i < BKT_SIZE; i += 256) {
            int n = n0 + i;
            if (n < N) {
                rowptr[n] = e0 + pos[i];
                dinv[n] = rsqrtf((float)cnt[i] + 1.0f);   // +1 self-loop
            }
        }
        __syncthreads();
        for (int e = e0 + tid; e < e1; e += 256) {
            unsigned v = gbin[e];
            int p = atomicAdd(&pos[v >> 23], 1);
            col[e0 + p] = (int)(v & 0x7FFFFFu);
        }
    }
}

// ---------------- MFMA GEMM: out[N,64] = bf16((A[N,K] @ W) * dinv[row]) ----------------
// Row-major in/out (R4-verified). xws row = 128 B: the aggregate's 8-lane groups
// consume full lines.
template<int K, typename AT>
__global__ __launch_bounds__(256) void k_gemm_mfma(const AT* __restrict__ A,
        const ushort_t* __restrict__ Bp, const float* __restrict__ dinv,
        ushort_t* __restrict__ out, int N) {
    int wave = threadIdx.x >> 6, lane = threadIdx.x & 63;
    int m = lane & 15, q = lane >> 4;
    int row0 = blockIdx.x * 64 + wave * 16;
    int arow = row0 + m;
    int arowc = (arow < N) ? arow : (N - 1);
    f32x4 acc[4] = {};
    #pragma unroll
    for (int s = 0; s < K / 32; ++s) {
        bf16x8 af;
        if constexpr (sizeof(AT) == 4) {
            const float* ap = (const float*)A + (size_t)arowc * K + s * 32 + q * 8;
            float4 x0 = *(const float4*)ap;
            float4 x1 = *(const float4*)(ap + 4);
            af[0] = (short)f2bf(x0.x); af[1] = (short)f2bf(x0.y);
            af[2] = (short)f2bf(x0.z); af[3] = (short)f2bf(x0.w);
            af[4] = (short)f2bf(x1.x); af[5] = (short)f2bf(x1.y);
            af[6] = (short)f2bf(x1.z); af[7] = (short)f2bf(x1.w);
        } else {
            af = *(const bf16x8*)((const ushort_t*)A + (size_t)arowc * K + s * 32 + q * 8);
        }
        #pragma unroll
        for (int t = 0; t < 4; ++t) {
            bf16x8 bf = *(const bf16x8*)(Bp + (size_t)((s * 4 + t) * 64 + lane) * 8);
            acc[t] = __builtin_amdgcn_mfma_f32_16x16x32_bf16(af, bf, acc[t], 0, 0, 0);
        }
    }
    // C/D layout: col = lane&15, row = q*4 + r  [m89-verified]
    int orow0 = row0 + q * 4;
    float4 d4 = *(const float4*)(dinv + orow0);   // ws slack makes OOB read safe
    #pragma unroll
    for (int r = 0; r < 4; ++r) {
        int row = orow0 + r;
        if (row < N) {
            float dn = (r == 0) ? d4.x : (r == 1) ? d4.y : (r == 2) ? d4.z : d4.w;
            #pragma unroll
            for (int t = 0; t < 4; ++t)
                out[(size_t)row * 64 + t * 16 + m] = f2bf(acc[t][r] * dn);
        }
    }
}

// ---------------- pull aggregation: 8 lanes/node, 8 nodes/wave (R4-verified) --------
// lane i of a group covers features i*8..i*8+7 (u16x8 = 16B loads); the 8 lanes of
// a group tile one full 128 B row line (100% line utilization), and the 8-edge
// unroll keeps 64 lines in flight per wave (MLP). R5/R6 slice variants broke one
// of these two properties each and were 2x slower — do not shard features.
__global__ __launch_bounds__(256) void k_aggregate(const ushort_t* __restrict__ xws,
        const int* __restrict__ rowptr, const int* __restrict__ col,
        const float* __restrict__ dinv, const float* __restrict__ bias,
        float* __restrict__ outf, ushort_t* __restrict__ outb, int N, int relu_bf16) {
    int n = (blockIdx.x * 256 + threadIdx.x) >> 3;
    int i = threadIdx.x & 7;
    if (n >= N) return;
    int beg = rowptr[n], end = rowptr[n + 1];
    float dn = dinv[n];
    const ushort_t* base = xws + i * 8;
    u16x8 sv = *(const u16x8*)(base + (size_t)n * 64);
    float a[8];
    #pragma unroll
    for (int k = 0; k < 8; ++k) a[k] = bf2f(sv[k]);   // self-loop term
    int e = beg;
    for (; e + 8 <= end; e += 8) {
        int c[8];
        #pragma unroll
        for (int j = 0; j < 8; ++j) c[j] = col[e + j];
        u16x8 v[8];
        #pragma unroll
        for (int j = 0; j < 8; ++j) v[j] = *(const u16x8*)(base + (size_t)c[j] * 64);
        #pragma unroll
        for (int j = 0; j < 8; ++j)
            #pragma unroll
            for (int k = 0; k < 8; ++k) a[k] += bf2f(v[j][k]);
    }
    if (e + 4 <= end) {
        int c[4];
        #pragma unroll
        for (int j = 0; j < 4; ++j) c[j] = col[e + j];
        u16x8 v[4];
        #pragma unroll
        for (int j = 0; j < 4; ++j) v[j] = *(const u16x8*)(base + (size_t)c[j] * 64);
        #pragma unroll
        for (int j = 0; j < 4; ++j)
            #pragma unroll
            for (int k = 0; k < 8; ++k) a[k] += bf2f(v[j][k]);
        e += 4;
    }
    for (; e < end; ++e) {
        u16x8 v = *(const u16x8*)(base + (size_t)col[e] * 64);
        #pragma unroll
        for (int k = 0; k < 8; ++k) a[k] += bf2f(v[k]);
    }
    float4 b0 = *(const float4*)(bias + i * 8);
    float4 b1 = *(const float4*)(bias + i * 8 + 4);
    float r[8];
    r[0] = dn * a[0] + b0.x; r[1] = dn * a[1] + b0.y;
    r[2] = dn * a[2] + b0.z; r[3] = dn * a[3] + b0.w;
    r[4] = dn * a[4] + b1.x; r[5] = dn * a[5] + b1.y;
    r[6] = dn * a[6] + b1.z; r[7] = dn * a[7] + b1.w;
    if (relu_bf16) {
        u16x8 o;
        #pragma unroll
        for (int k = 0; k < 8; ++k) o[k] = f2bf(fmaxf(r[k], 0.f));
        *(u16x8*)(outb + (size_t)n * 64 + i * 8) = o;
    } else {
        float4 o0 = {r[0], r[1], r[2], r[3]};
        float4 o1 = {r[4], r[5], r[6], r[7]};
        *(float4*)(outf + (size_t)n * 64 + i * 8) = o0;
        *(float4*)(outf + (size_t)n * 64 + i * 8 + 4) = o1;
    }
}

// ---------------- launch ----------------

extern "C" void kernel_launch(void* const* d_in, const int* in_sizes, int n_in,
                              void* d_out, int out_size, void* d_ws, size_t ws_size,
                              hipStream_t stream) {
    const float* x  = (const float*)d_in[0];
    const int*   ei = (const int*)d_in[1];
    const float* W1 = (const float*)d_in[2];
    const float* b1 = (const float*)d_in[3];
    const float* W2 = (const float*)d_in[4];
    const float* b2 = (const float*)d_in[5];
    float* out = (float*)d_out;

    const int N = in_sizes[0] / IN_F;
    const int E = in_sizes[1] / 2;
    const int* src = ei;        // edge_index[0]
    const int* dst = ei + E;    // edge_index[1]

    char* ws = (char*)d_ws;
    const size_t MB = 1u << 20;
    int*      bbase   = (int*)     (ws + 4096);              // 257 ints
    int*      gbase   = (int*)     (ws + 8192);              // 256 ints
    int*      gcount  = (int*)     (ws + 12288);             // 256 ints
    ushort_t* Bp1     = (ushort_t*)(ws + 16384);             // 8192 bf16 (16 KB)
    ushort_t* Bp2     = (ushort_t*)(ws + 49152);             // 4096 bf16 (8 KB)
    int*      rowptr  = (int*)     (ws + 1 * MB);            // N+1 ints
    float*    dinv    = (float*)   (ws + 2 * MB);            // N floats (+slack)
    unsigned* gbin    = (unsigned*)(ws + 3 * MB);            // E uints (6.4 MB)
    int*      ghist   = (int*)     (ws + 10 * MB);           // nbE*256 ints (~400 KB)
    int*      col     = (int*)     (ws + 11 * MB);           // E ints  (6.4 MB)
    ushort_t* xws     = (ushort_t*)(ws + 20 * MB);           // N*64 bf16 (12.8 MB)
    ushort_t* h       = (ushort_t*)(ws + 36 * MB);           // N*64 bf16 (12.8 MB)

    int nbE = (E + CHUNK - 1) / CHUNK;                       // 391 (<= 512 for colscan)
    int nbB = (N + BKT_SIZE - 1) / BKT_SIZE;                 // 196 buckets (<= 256)
    const int nbG = (N + 63) / 64;                           // GEMM blocks
    const int nbA = (N * 8 + 255) / 256;                     // aggregate blocks
    int Ev = E, Nv = N;

    // single cooperative kernel for the whole CSR build (4 launch gaps removed)
    void* kargs[] = {
        (void*)&src, (void*)&dst, (void*)&ghist, (void*)&gcount, (void*)&gbase,
        (void*)&bbase, (void*)&rowptr, (void*)&dinv, (void*)&gbin, (void*)&col,
        (void*)&W1, (void*)&W2, (void*)&Bp1, (void*)&Bp2,
        (void*)&Ev, (void*)&Nv, (void*)&nbE, (void*)&nbB };
    hipLaunchCooperativeKernel((void*)k_csr, dim3(nbE + 48), dim3(256),
                               kargs, 0, stream);

    // layer 1: xws = bf16((x @ W1) * dinv) ; h = bf16(relu(dinv*(sum+self) + b1))
    k_gemm_mfma<IN_F, float>   <<<nbG, 256, 0, stream>>>(x, Bp1, dinv, xws, N);
    k_aggregate<<<nbA, 256, 0, stream>>>(xws, rowptr, col, dinv, b1, nullptr, h, N, 1);

    // layer 2: xws = bf16((h @ W2) * dinv) ; out = dinv*(sum+self) + b2  (fp32)
    k_gemm_mfma<HID_F, ushort_t><<<nbG, 256, 0, stream>>>(h, Bp2, dinv, xws, N);
    k_aggregate<<<nbA, 256, 0, stream>>>(xws, rowptr, col, dinv, b2, out, nullptr, N, 0);
}

// Round 9
// 229.492 us; speedup vs baseline: 2.0278x; 2.0278x over previous
//
#include <hip/hip_runtime.h>

#define IN_F 128
#define HID_F 64
#define BKT_SHIFT 9            // 512 nodes per bucket (R4-verified geometry)
#define BKT_SIZE 512
#define CHUNK 4096             // edges per block in binning kernels

typedef unsigned short ushort_t;
typedef __attribute__((ext_vector_type(8))) short bf16x8;
typedef __attribute__((ext_vector_type(8))) unsigned short u16x8;
typedef __attribute__((ext_vector_type(4))) float f32x4;

__device__ inline ushort_t f2bf(float f) {     // RNE fp32 -> bf16 bits
    unsigned u = __float_as_uint(f);
    u += 0x7FFFu + ((u >> 16) & 1u);
    return (ushort_t)(u >> 16);
}
__device__ inline float bf2f(ushort_t u) {
    return __uint_as_float((unsigned)u << 16);
}

// ---------------- CSR build: atomic-free 2-level bucket sort by dst ----------------
// pack: (dst & 511) << 23 | src   (needs src < 2^23, nodes/bucket <= 512)

__global__ __launch_bounds__(256) void k_hist_pack(const int* __restrict__ dst,
        int* __restrict__ ghist, int E, int nbE,
        const float* __restrict__ W1, const float* __restrict__ W2,
        ushort_t* __restrict__ Bp1, ushort_t* __restrict__ Bp2) {
    int tid = threadIdx.x;
    if ((int)blockIdx.x >= nbE) {
        // W pre-pack into MFMA B-fragment order (bf16).
        // B-frag (16x16x32): lane holds B[k = (lane>>4)*8 + j][n = lane&15], j=0..7.
        int id = ((int)blockIdx.x - nbE) * 256 + tid;
        int iw = (id < 8192) ? id : id - 8192;
        int j = iw & 7, lane = (iw >> 3) & 63, t = (iw >> 9) & 3, s = iw >> 11;
        int k = s * 32 + ((lane >> 4) << 3) + j;
        int n = t * 16 + (lane & 15);
        if (id < 8192)        Bp1[iw] = f2bf(W1[k * 64 + n]);   // K=128: s in 0..3
        else if (id < 12288)  Bp2[iw] = f2bf(W2[k * 64 + n]);   // K=64 : s in 0..1
        return;
    }
    __shared__ int hist[256];
    hist[tid] = 0;
    __syncthreads();
    int e0 = blockIdx.x * CHUNK, e1 = min(e0 + CHUNK, E);
    for (int e = e0 + tid; e < e1; e += 256)
        atomicAdd(&hist[dst[e] >> BKT_SHIFT], 1);
    __syncthreads();
    ghist[blockIdx.x * 256 + tid] = hist[tid];
}

// 256 blocks, one per bucket: parallel exclusive scan over the nb per-block
// counts of this bucket (2 elements/thread, nb <= 512). totals -> gcount.
__global__ __launch_bounds__(256) void k_colscan(int* __restrict__ ghist,
        int* __restrict__ gcount, int nb) {
    __shared__ int s[256];
    int t = threadIdx.x;
    int b = blockIdx.x;
    int j0 = 2 * t, j1 = 2 * t + 1;
    int v0 = (j0 < nb) ? ghist[j0 * 256 + b] : 0;
    int v1 = (j1 < nb) ? ghist[j1 * 256 + b] : 0;
    int p = v0 + v1;
    s[t] = p;
    __syncthreads();
    for (int off = 1; off < 256; off <<= 1) {
        int v = (t >= off) ? s[t - off] : 0;
        __syncthreads();
        s[t] += v;
        __syncthreads();
    }
    int excl = s[t] - p;
    if (j0 < nb) ghist[j0 * 256 + b] = excl;
    if (j1 < nb) ghist[j1 * 256 + b] = excl + v0;
    if (t == 255) gcount[b] = s[255];
}

// scatter into bucket-contiguous gbin; per-block cursors = ghist offset + bucket
// base, where the 256-bucket base prefix is recomputed locally from gcount
// (k_bscan eliminated — 256-elem LDS scan is cheap and runs concurrently).
__global__ __launch_bounds__(256) void k_scatter(const int* __restrict__ src,
        const int* __restrict__ dst, const int* __restrict__ ghist,
        const int* __restrict__ gcount, unsigned* __restrict__ gbin, int E) {
    __shared__ int cur[256];
    __shared__ int s[256];
    int tid = threadIdx.x;
    int gc = gcount[tid];
    s[tid] = gc;
    __syncthreads();
    for (int off = 1; off < 256; off <<= 1) {
        int v = (tid >= off) ? s[tid - off] : 0;
        __syncthreads();
        s[tid] += v;
        __syncthreads();
    }
    cur[tid] = ghist[blockIdx.x * 256 + tid] + (s[tid] - gc);
    __syncthreads();
    int e0 = blockIdx.x * CHUNK, e1 = min(e0 + CHUNK, E);
    for (int e = e0 + tid; e < e1; e += 256) {
        int d = dst[e];
        int b = d >> BKT_SHIFT;
        int p = atomicAdd(&cur[b], 1);
        gbin[p] = ((unsigned)(d & (BKT_SIZE - 1)) << 23) | (unsigned)src[e];
    }
}

// one block per bucket: bucket window from local gcount scan, per-node count (LDS),
// LDS scan of 512, write rowptr/dinv coalesced, then scatter col in the hot window.
__global__ __launch_bounds__(256) void k_fill2(const unsigned* __restrict__ gbin,
        const int* __restrict__ gcount, int* __restrict__ rowptr,
        float* __restrict__ dinv, int* __restrict__ col, int N, int E) {
    __shared__ int cnt[BKT_SIZE];
    __shared__ int pos[BKT_SIZE];
    __shared__ int s[256];
    int tid = threadIdx.x;
    int b = blockIdx.x;
    // local scan of gcount -> bucket window [e0, e1)
    int gc = gcount[tid];
    s[tid] = gc;
    __syncthreads();
    for (int off = 1; off < 256; off <<= 1) {
        int v = (tid >= off) ? s[tid - off] : 0;
        __syncthreads();
        s[tid] += v;
        __syncthreads();
    }
    int e0 = (b > 0) ? s[b - 1] : 0;     // broadcast reads
    int e1 = s[b];
    if (b == 0 && tid == 0) rowptr[N] = E;
    __syncthreads();                      // s[] reused below
    cnt[tid] = 0; cnt[tid + 256] = 0;
    __syncthreads();
    for (int e = e0 + tid; e < e1; e += 256)
        atomicAdd(&cnt[gbin[e] >> 23], 1);
    __syncthreads();
    int c0 = cnt[2 * tid], c1 = cnt[2 * tid + 1];
    int p2 = c0 + c1;
    s[tid] = p2;
    __syncthreads();
    for (int off = 1; off < 256; off <<= 1) {
        int v = (tid >= off) ? s[tid - off] : 0;
        __syncthreads();
        s[tid] += v;
        __syncthreads();
    }
    int excl = s[tid] - p2;
    pos[2 * tid] = excl;
    pos[2 * tid + 1] = excl + c0;
    __syncthreads();
    int n0 = b << BKT_SHIFT;
    #pragma unroll
    for (int i = tid; i < BKT_SIZE; i += 256) {
        int n = n0 + i;
        if (n < N) {
            rowptr[n] = e0 + pos[i];
            dinv[n] = rsqrtf((float)cnt[i] + 1.0f);   // +1 self-loop
        }
    }
    __syncthreads();
    for (int e = e0 + tid; e < e1; e += 256) {
        unsigned v = gbin[e];
        int p = atomicAdd(&pos[v >> 23], 1);
        col[e0 + p] = (int)(v & 0x7FFFFFu);
    }
}

// ---------------- MFMA GEMM: out[N,64] = bf16((A[N,K] @ W) * dinv[row]) ----------------
template<int K, typename AT>
__global__ __launch_bounds__(256) void k_gemm_mfma(const AT* __restrict__ A,
        const ushort_t* __restrict__ Bp, const float* __restrict__ dinv,
        ushort_t* __restrict__ out, int N) {
    int wave = threadIdx.x >> 6, lane = threadIdx.x & 63;
    int m = lane & 15, q = lane >> 4;
    int row0 = blockIdx.x * 64 + wave * 16;
    int arow = row0 + m;
    int arowc = (arow < N) ? arow : (N - 1);
    f32x4 acc[4] = {};
    #pragma unroll
    for (int s = 0; s < K / 32; ++s) {
        bf16x8 af;
        if constexpr (sizeof(AT) == 4) {
            const float* ap = (const float*)A + (size_t)arowc * K + s * 32 + q * 8;
            float4 x0 = *(const float4*)ap;
            float4 x1 = *(const float4*)(ap + 4);
            af[0] = (short)f2bf(x0.x); af[1] = (short)f2bf(x0.y);
            af[2] = (short)f2bf(x0.z); af[3] = (short)f2bf(x0.w);
            af[4] = (short)f2bf(x1.x); af[5] = (short)f2bf(x1.y);
            af[6] = (short)f2bf(x1.z); af[7] = (short)f2bf(x1.w);
        } else {
            af = *(const bf16x8*)((const ushort_t*)A + (size_t)arowc * K + s * 32 + q * 8);
        }
        #pragma unroll
        for (int t = 0; t < 4; ++t) {
            bf16x8 bf = *(const bf16x8*)(Bp + (size_t)((s * 4 + t) * 64 + lane) * 8);
            acc[t] = __builtin_amdgcn_mfma_f32_16x16x32_bf16(af, bf, acc[t], 0, 0, 0);
        }
    }
    // C/D layout: col = lane&15, row = q*4 + r  [m89-verified]
    int orow0 = row0 + q * 4;
    float4 d4 = *(const float4*)(dinv + orow0);   // ws slack makes OOB read safe
    #pragma unroll
    for (int r = 0; r < 4; ++r) {
        int row = orow0 + r;
        if (row < N) {
            float dn = (r == 0) ? d4.x : (r == 1) ? d4.y : (r == 2) ? d4.z : d4.w;
            #pragma unroll
            for (int t = 0; t < 4; ++t)
                out[(size_t)row * 64 + t * 16 + m] = f2bf(acc[t][r] * dn);
        }
    }
}

// ---------------- fused aggregate-1 + gemm2 ----------------
// Phase A (R4-verified gather): 8 lanes/node, 8 nodes/wave, 8-edge unroll; computes
// h[n] = relu(dinv*(sum+self)+b1) for the block's 32 nodes, staged in LDS (bf16,
// [32][72] pad -> 2-way bank alias = free). Phase B: 4 MFMA per wave against the
// pre-packed Bp2 -> xws2 = bf16((h @ W2) * dinv), same layouts as k_gemm_mfma.
// Saves the gemm2 launch + 25.6 MB of h write/read traffic.
__global__ __launch_bounds__(256) void k_agg_gemm(const ushort_t* __restrict__ xws,
        const int* __restrict__ rowptr, const int* __restrict__ col,
        const float* __restrict__ dinv, const float* __restrict__ bias,
        const ushort_t* __restrict__ Bp2, ushort_t* __restrict__ out2, int N) {
    __shared__ ushort_t hl[32][72];                 // 4.5 KB, +8 pad breaks 128B stride
    int tid = threadIdx.x;
    int nl = tid >> 3;                              // node-local 0..31
    int i = tid & 7;                                // feature slice 0..7
    int n0 = blockIdx.x * 32;
    int n = n0 + nl;
    u16x8 hz = {};
    if (n < N) {
        int beg = rowptr[n], end = rowptr[n + 1];
        float dn = dinv[n];
        const ushort_t* base = xws + i * 8;
        u16x8 sv = *(const u16x8*)(base + (size_t)n * 64);
        float a[8];
        #pragma unroll
        for (int k = 0; k < 8; ++k) a[k] = bf2f(sv[k]);   // self-loop term
        int e = beg;
        for (; e + 8 <= end; e += 8) {
            int c[8];
            #pragma unroll
            for (int j = 0; j < 8; ++j) c[j] = col[e + j];
            u16x8 v[8];
            #pragma unroll
            for (int j = 0; j < 8; ++j) v[j] = *(const u16x8*)(base + (size_t)c[j] * 64);
            #pragma unroll
            for (int j = 0; j < 8; ++j)
                #pragma unroll
                for (int k = 0; k < 8; ++k) a[k] += bf2f(v[j][k]);
        }
        if (e + 4 <= end) {
            int c[4];
            #pragma unroll
            for (int j = 0; j < 4; ++j) c[j] = col[e + j];
            u16x8 v[4];
            #pragma unroll
            for (int j = 0; j < 4; ++j) v[j] = *(const u16x8*)(base + (size_t)c[j] * 64);
            #pragma unroll
            for (int j = 0; j < 4; ++j)
                #pragma unroll
                for (int k = 0; k < 8; ++k) a[k] += bf2f(v[j][k]);
            e += 4;
        }
        for (; e < end; ++e) {
            u16x8 v = *(const u16x8*)(base + (size_t)col[e] * 64);
            #pragma unroll
            for (int k = 0; k < 8; ++k) a[k] += bf2f(v[k]);
        }
        float4 b0 = *(const float4*)(bias + i * 8);
        float4 b1 = *(const float4*)(bias + i * 8 + 4);
        float r[8];
        r[0] = dn * a[0] + b0.x; r[1] = dn * a[1] + b0.y;
        r[2] = dn * a[2] + b0.z; r[3] = dn * a[3] + b0.w;
        r[4] = dn * a[4] + b1.x; r[5] = dn * a[5] + b1.y;
        r[6] = dn * a[6] + b1.z; r[7] = dn * a[7] + b1.w;
        #pragma unroll
        for (int k = 0; k < 8; ++k) hz[k] = f2bf(fmaxf(r[k], 0.f));
    }
    *(u16x8*)&hl[nl][i * 8] = hz;
    __syncthreads();
    // ---- Phase B: xws2[32,64] = bf16((h @ W2) * dinv) via MFMA ----
    int w = tid >> 6, lane = tid & 63;
    int m = lane & 15, q = lane >> 4;
    int mt = w & 1;                  // M-tile (rows mt*16..mt*16+15)
    int nt0 = (w >> 1) << 1;         // this wave's two N-tiles
    f32x4 acc[2] = {};
    #pragma unroll
    for (int s = 0; s < 2; ++s) {
        bf16x8 af = *(const bf16x8*)&hl[mt * 16 + m][s * 32 + q * 8];
        #pragma unroll
        for (int tt = 0; tt < 2; ++tt) {
            bf16x8 bf = *(const bf16x8*)(Bp2 + (size_t)((s * 4 + nt0 + tt) * 64 + lane) * 8);
            acc[tt] = __builtin_amdgcn_mfma_f32_16x16x32_bf16(af, bf, acc[tt], 0, 0, 0);
        }
    }
    // C/D layout: col = lane&15, row = q*4 + r  [m89-verified]
    int orow0 = n0 + mt * 16 + q * 4;
    float4 d4 = *(const float4*)(dinv + orow0);
    #pragma unroll
    for (int r = 0; r < 4; ++r) {
        int row = orow0 + r;
        if (row < N) {
            float dn = (r == 0) ? d4.x : (r == 1) ? d4.y : (r == 2) ? d4.z : d4.w;
            #pragma unroll
            for (int tt = 0; tt < 2; ++tt)
                out2[(size_t)row * 64 + (nt0 + tt) * 16 + m] = f2bf(acc[tt][r] * dn);
        }
    }
}

// ---------------- pull aggregation (layer 2 final): R4-verified pattern --------------
__global__ __launch_bounds__(256) void k_aggregate(const ushort_t* __restrict__ xws,
        const int* __restrict__ rowptr, const int* __restrict__ col,
        const float* __restrict__ dinv, const float* __restrict__ bias,
        float* __restrict__ outf, int N) {
    int n = (blockIdx.x * 256 + threadIdx.x) >> 3;
    int i = threadIdx.x & 7;
    if (n >= N) return;
    int beg = rowptr[n], end = rowptr[n + 1];
    float dn = dinv[n];
    const ushort_t* base = xws + i * 8;
    u16x8 sv = *(const u16x8*)(base + (size_t)n * 64);
    float a[8];
    #pragma unroll
    for (int k = 0; k < 8; ++k) a[k] = bf2f(sv[k]);   // self-loop term
    int e = beg;
    for (; e + 8 <= end; e += 8) {
        int c[8];
        #pragma unroll
        for (int j = 0; j < 8; ++j) c[j] = col[e + j];
        u16x8 v[8];
        #pragma unroll
        for (int j = 0; j < 8; ++j) v[j] = *(const u16x8*)(base + (size_t)c[j] * 64);
        #pragma unroll
        for (int j = 0; j < 8; ++j)
            #pragma unroll
            for (int k = 0; k < 8; ++k) a[k] += bf2f(v[j][k]);
    }
    if (e + 4 <= end) {
        int c[4];
        #pragma unroll
        for (int j = 0; j < 4; ++j) c[j] = col[e + j];
        u16x8 v[4];
        #pragma unroll
        for (int j = 0; j < 4; ++j) v[j] = *(const u16x8*)(base + (size_t)c[j] * 64);
        #pragma unroll
        for (int j = 0; j < 4; ++j)
            #pragma unroll
            for (int k = 0; k < 8; ++k) a[k] += bf2f(v[j][k]);
        e += 4;
    }
    for (; e < end; ++e) {
        u16x8 v = *(const u16x8*)(base + (size_t)col[e] * 64);
        #pragma unroll
        for (int k = 0; k < 8; ++k) a[k] += bf2f(v[k]);
    }
    float4 b0 = *(const float4*)(bias + i * 8);
    float4 b1 = *(const float4*)(bias + i * 8 + 4);
    float4 o0 = {dn * a[0] + b0.x, dn * a[1] + b0.y, dn * a[2] + b0.z, dn * a[3] + b0.w};
    float4 o1 = {dn * a[4] + b1.x, dn * a[5] + b1.y, dn * a[6] + b1.z, dn * a[7] + b1.w};
    *(float4*)(outf + (size_t)n * 64 + i * 8) = o0;
    *(float4*)(outf + (size_t)n * 64 + i * 8 + 4) = o1;
}

// ---------------- launch ----------------

extern "C" void kernel_launch(void* const* d_in, const int* in_sizes, int n_in,
                              void* d_out, int out_size, void* d_ws, size_t ws_size,
                              hipStream_t stream) {
    const float* x  = (const float*)d_in[0];
    const int*   ei = (const int*)d_in[1];
    const float* W1 = (const float*)d_in[2];
    const float* b1 = (const float*)d_in[3];
    const float* W2 = (const float*)d_in[4];
    const float* b2 = (const float*)d_in[5];
    float* out = (float*)d_out;

    const int N = in_sizes[0] / IN_F;
    const int E = in_sizes[1] / 2;
    const int* src = ei;        // edge_index[0]
    const int* dst = ei + E;    // edge_index[1]

    char* ws = (char*)d_ws;
    const size_t MB = 1u << 20;
    int*      gcount  = (int*)     (ws + 12288);             // 256 ints
    ushort_t* Bp1     = (ushort_t*)(ws + 16384);             // 8192 bf16 (16 KB)
    ushort_t* Bp2     = (ushort_t*)(ws + 49152);             // 4096 bf16 (8 KB)
    int*      rowptr  = (int*)     (ws + 1 * MB);            // N+1 ints
    float*    dinv    = (float*)   (ws + 2 * MB);            // N floats (+slack)
    unsigned* gbin    = (unsigned*)(ws + 3 * MB);            // E uints (6.4 MB)
    int*      ghist   = (int*)     (ws + 10 * MB);           // nbE*256 ints (~400 KB)
    int*      col     = (int*)     (ws + 11 * MB);           // E ints  (6.4 MB)
    ushort_t* xws     = (ushort_t*)(ws + 20 * MB);           // N*64 bf16 (12.8 MB)
    ushort_t* xws2    = (ushort_t*)(ws + 36 * MB);           // N*64 bf16 (12.8 MB)

    const int nbE = (E + CHUNK - 1) / CHUNK;                 // 391 (<= 512 for colscan)
    const int nbB = (N + BKT_SIZE - 1) / BKT_SIZE;           // 196 buckets (<= 256)
    const int nbG = (N + 63) / 64;                           // GEMM blocks
    const int nbA = (N * 8 + 255) / 256;                     // aggregate blocks (32 nodes/blk)

    k_hist_pack<<<nbE + 48, 256, 0, stream>>>(dst, ghist, E, nbE, W1, W2, Bp1, Bp2);
    k_colscan<<<256, 256, 0, stream>>>(ghist, gcount, nbE);
    k_scatter<<<nbE, 256, 0, stream>>>(src, dst, ghist, gcount, gbin, E);
    k_fill2  <<<nbB, 256, 0, stream>>>(gbin, gcount, rowptr, dinv, col, N, E);

    // layer 1 GEMM: xws = bf16((x @ W1) * dinv)
    k_gemm_mfma<IN_F, float><<<nbG, 256, 0, stream>>>(x, Bp1, dinv, xws, N);
    // fused: h = relu(dinv*(sum+self)+b1) (LDS only) ; xws2 = bf16((h @ W2) * dinv)
    k_agg_gemm<<<nbA, 256, 0, stream>>>(xws, rowptr, col, dinv, b1, Bp2, xws2, N);
    // layer 2 aggregate: out = dinv*(sum+self) + b2  (fp32)
    k_aggregate<<<nbA, 256, 0, stream>>>(xws2, rowptr, col, dinv, b2, out, N);
}